// Round 1
// baseline (255.064 us; speedup 1.0000x reference)
//
#include <hip/hip_runtime.h>
#include <math.h>

namespace {

constexpr float kAlpha   = 0.75f;
constexpr int   kNumNeg  = 10000;
constexpr int   kNumHard = 100;
constexpr int   kRatio   = 100;
constexpr int   kB       = 8;
constexpr int   kN       = 64 * 128 * 128;   // 1048576
constexpr int   kBlocksPerB = 128;
constexpr int   kTpbA    = 256;
constexpr int   kSortN   = 16384;            // next pow2 >= kNumNeg
constexpr int   kTpbC    = 1024;

__device__ __forceinline__ float loss_at(float pred, float target, float mask) {
    float prob = 1.0f / (1.0f + expf(-pred));
    prob = fminf(fmaxf(prob, 1.0e-4f), 1.0f - 1.0e-4f);
    bool pos = (target == 1.0f);
    float alpha_f = pos ? kAlpha : (1.0f - kAlpha);
    float pt = pos ? (1.0f - prob) : prob;
    float focal_w = alpha_f * pt * pt;
    float bce = fmaxf(pred, 0.0f) - pred * target + log1pf(expf(-fabsf(pred)));
    float loss = (mask == 0.0f) ? focal_w * bce : 0.0f;
    if (pos && prob < 0.8f) loss *= 4.0f;
    return loss;
}

// Stage A: per-(batch, block) partial num_pos / pos_sum.
// Only `target` is streamed; pred/mask are touched only at rare positives.
__global__ void __launch_bounds__(kTpbA) pos_reduce_kernel(
        const float* __restrict__ pred, const float* __restrict__ target,
        const float* __restrict__ mask, float* __restrict__ partials) {
    const int b = blockIdx.y;
    const size_t base = (size_t)b * kN;
    const float4* t4 = (const float4*)(target + base);
    const int nvec = kN / 4;

    float cnt = 0.0f, psum = 0.0f;
    for (int i = blockIdx.x * kTpbA + threadIdx.x; i < nvec; i += kTpbA * kBlocksPerB) {
        float4 tv = t4[i];
        float tvv[4] = {tv.x, tv.y, tv.z, tv.w};
        #pragma unroll
        for (int c = 0; c < 4; ++c) {
            if (tvv[c] == 1.0f) {
                int gi = i * 4 + c;
                cnt += 1.0f;
                psum += loss_at(pred[base + gi], 1.0f, mask[base + gi]);
            }
        }
    }
    #pragma unroll
    for (int off = 32; off > 0; off >>= 1) {
        cnt  += __shfl_down(cnt, off);
        psum += __shfl_down(psum, off);
    }
    __shared__ float sc[kTpbA / 64], sp[kTpbA / 64];
    const int wave = threadIdx.x / 64, lane = threadIdx.x % 64;
    if (lane == 0) { sc[wave] = cnt; sp[wave] = psum; }
    __syncthreads();
    if (threadIdx.x == 0) {
        float c = 0.0f, p = 0.0f;
        for (int w = 0; w < kTpbA / 64; ++w) { c += sc[w]; p += sp[w]; }
        float* slot = partials + ((size_t)b * kBlocksPerB + blockIdx.x) * 2;
        slot[0] = c; slot[1] = p;
    }
}

// Stage B: one block per batch. Gather 10K candidate losses, bitonic-sort
// descending in LDS, sum top-k (k from num_pos), write per-batch loss.
__global__ void __launch_bounds__(kTpbC) topk_kernel(
        const float* __restrict__ pred, const float* __restrict__ target,
        const float* __restrict__ mask, const int* __restrict__ neg_idx,
        const float* __restrict__ partials, float* __restrict__ batch_loss) {
    __shared__ float s[kSortN];                  // 64 KiB
    __shared__ float sc[kBlocksPerB], sp[kBlocksPerB];
    __shared__ float s_stat[2];                  // num_pos, pos_sum
    const int b = blockIdx.x;
    const int tid = threadIdx.x;
    const size_t base = (size_t)b * kN;

    if (tid < kBlocksPerB) {
        const float* slot = partials + ((size_t)b * kBlocksPerB + tid) * 2;
        sc[tid] = slot[0]; sp[tid] = slot[1];
    }

    const int* idx = neg_idx + (size_t)b * kNumNeg;
    for (int j = tid; j < kSortN; j += kTpbC) {
        float v = -2.0f;                         // padding: sorts last, fails v>=0
        if (j < kNumNeg) {
            int gi = idx[j];
            float tg = target[base + gi];
            if (tg == 1.0f) v = -1.0f;           // positive sentinel
            else v = loss_at(pred[base + gi], tg, mask[base + gi]);
        }
        s[j] = v;
    }
    __syncthreads();
    if (tid == 0) {
        float c = 0.0f, p = 0.0f;
        for (int w = 0; w < kBlocksPerB; ++w) { c += sc[w]; p += sp[w]; }
        s_stat[0] = c; s_stat[1] = p;
    }

    // bitonic sort, descending overall
    for (unsigned k = 2; k <= (unsigned)kSortN; k <<= 1) {
        for (unsigned j = k >> 1; j > 0; j >>= 1) {
            __syncthreads();
            for (unsigned i = tid; i < (unsigned)kSortN; i += kTpbC) {
                unsigned ixj = i ^ j;
                if (ixj > i) {
                    bool up = ((i & k) != 0);    // final stage: descending
                    float a = s[i], c = s[ixj];
                    if ((a > c) == up) { s[i] = c; s[ixj] = a; }
                }
            }
        }
    }
    __syncthreads();

    const float num_posf = s_stat[0];
    const int num_pos = (int)num_posf;
    const int kkeep = (num_pos > 0) ? min(kRatio * num_pos, kNumNeg) : kNumHard;
    float nsum = 0.0f;
    for (int j = tid; j < kkeep; j += kTpbC) {
        float v = s[j];
        if (v >= 0.0f) nsum += v;
    }
    #pragma unroll
    for (int off = 32; off > 0; off >>= 1) nsum += __shfl_down(nsum, off);
    __shared__ float sw[kTpbC / 64];
    const int wave = tid / 64, lane = tid % 64;
    if (lane == 0) sw[wave] = nsum;
    __syncthreads();
    if (tid == 0) {
        float t = 0.0f;
        for (int w = 0; w < kTpbC / 64; ++w) t += sw[w];
        batch_loss[b] = (s_stat[1] + t) / fmaxf(num_posf, 1.0f);
    }
}

__global__ void finalize_kernel(const float* __restrict__ batch_loss,
                                float* __restrict__ out) {
    if (threadIdx.x == 0) {
        float s = 0.0f;
        for (int b = 0; b < kB; ++b) s += batch_loss[b];
        out[0] = s / (float)kB;
    }
}

} // namespace

extern "C" void kernel_launch(void* const* d_in, const int* in_sizes, int n_in,
                              void* d_out, int out_size, void* d_ws, size_t ws_size,
                              hipStream_t stream) {
    const float* pred   = (const float*)d_in[0];
    const float* target = (const float*)d_in[1];
    const float* mask   = (const float*)d_in[2];
    const int*   negidx = (const int*)d_in[3];
    float* ws = (float*)d_ws;
    float* partials   = ws;                          // kB*kBlocksPerB*2 floats
    float* batch_loss = ws + kB * kBlocksPerB * 2;   // kB floats
    float* out = (float*)d_out;

    dim3 gridA(kBlocksPerB, kB);
    pos_reduce_kernel<<<gridA, dim3(kTpbA), 0, stream>>>(pred, target, mask, partials);
    topk_kernel<<<dim3(kB), dim3(kTpbC), 0, stream>>>(pred, target, mask, negidx,
                                                      partials, batch_loss);
    finalize_kernel<<<1, 64, 0, stream>>>(batch_loss, out);
}

// Round 2
// 68.324 us; speedup vs baseline: 3.7331x; 3.7331x over previous
//
#include <hip/hip_runtime.h>
#include <math.h>

namespace {

constexpr float kAlpha   = 0.75f;
constexpr int   kNumNeg  = 10000;
constexpr int   kNumHard = 100;
constexpr int   kRatio   = 100;
constexpr int   kB       = 8;
constexpr int   kN       = 64 * 128 * 128;   // 1048576
constexpr int   kBlocksPerB = 128;
constexpr int   kTpbA    = 256;
constexpr int   kTpbSel  = 1024;
constexpr unsigned kSentinel = 0xFFFFFFFFu;  // pos-in-idx / invalid marker

__device__ __forceinline__ float loss_at(float pred, float target, float mask) {
    float prob = 1.0f / (1.0f + expf(-pred));
    prob = fminf(fmaxf(prob, 1.0e-4f), 1.0f - 1.0e-4f);
    bool pos = (target == 1.0f);
    float alpha_f = pos ? kAlpha : (1.0f - kAlpha);
    float pt = pos ? (1.0f - prob) : prob;
    float focal_w = alpha_f * pt * pt;
    float bce = fmaxf(pred, 0.0f) - pred * target + log1pf(expf(-fabsf(pred)));
    float loss = (mask == 0.0f) ? focal_w * bce : 0.0f;
    if (pos && prob < 0.8f) loss *= 4.0f;
    return loss;
}

// Stage A: per-(batch, block) partial num_pos / pos_sum.
// Only `target` is streamed; pred/mask touched only at rare positives.
__global__ void __launch_bounds__(kTpbA) pos_reduce_kernel(
        const float* __restrict__ pred, const float* __restrict__ target,
        const float* __restrict__ mask, float* __restrict__ partials) {
    const int b = blockIdx.y;
    const size_t base = (size_t)b * kN;
    const float4* t4 = (const float4*)(target + base);
    const int nvec = kN / 4;

    float cnt = 0.0f, psum = 0.0f;
    for (int i = blockIdx.x * kTpbA + threadIdx.x; i < nvec; i += kTpbA * kBlocksPerB) {
        float4 tv = t4[i];
        float tvv[4] = {tv.x, tv.y, tv.z, tv.w};
        #pragma unroll
        for (int c = 0; c < 4; ++c) {
            if (tvv[c] == 1.0f) {
                int gi = i * 4 + c;
                cnt += 1.0f;
                psum += loss_at(pred[base + gi], 1.0f, mask[base + gi]);
            }
        }
    }
    #pragma unroll
    for (int off = 32; off > 0; off >>= 1) {
        cnt  += __shfl_down(cnt, off);
        psum += __shfl_down(psum, off);
    }
    __shared__ float sc[kTpbA / 64], sp[kTpbA / 64];
    const int wave = threadIdx.x / 64, lane = threadIdx.x % 64;
    if (lane == 0) { sc[wave] = cnt; sp[wave] = psum; }
    __syncthreads();
    if (threadIdx.x == 0) {
        float c = 0.0f, p = 0.0f;
        for (int w = 0; w < kTpbA / 64; ++w) { c += sc[w]; p += sp[w]; }
        float* slot = partials + ((size_t)b * kBlocksPerB + blockIdx.x) * 2;
        slot[0] = c; slot[1] = p;
    }
}

// Stage B: spread the random gathers over many CUs. One element per thread.
__global__ void __launch_bounds__(256) gather_kernel(
        const float* __restrict__ pred, const float* __restrict__ target,
        const float* __restrict__ mask, const int* __restrict__ neg_idx,
        unsigned* __restrict__ gvals) {
    const int b = blockIdx.y;
    const int j = blockIdx.x * blockDim.x + threadIdx.x;
    if (j >= kNumNeg) return;
    const size_t base = (size_t)b * kN;
    const int gi = neg_idx[(size_t)b * kNumNeg + j];
    const float tg = target[base + gi];
    unsigned outv;
    if (tg == 1.0f) {
        outv = kSentinel;                        // ref stores -1: never kept
    } else {
        float v = loss_at(pred[base + gi], tg, mask[base + gi]);
        outv = __float_as_uint(v);               // v >= 0, finite
    }
    gvals[(size_t)b * kNumNeg + j] = outv;
}

// Stage C: one block per batch. Exact top-k sum via 4-pass MSB radix select.
__global__ void __launch_bounds__(kTpbSel) select_kernel(
        const unsigned* __restrict__ gvals, const float* __restrict__ partials,
        float* __restrict__ batch_loss) {
    __shared__ unsigned s[kNumNeg];              // 40 KB
    __shared__ unsigned hist[256];
    __shared__ float red[kTpbSel / 64];
    __shared__ float sh_np, sh_ps, sh_m, sh_sumall;
    __shared__ unsigned sh_krem, sh_prefix, sh_mask;
    __shared__ int sh_done;

    const int b = blockIdx.x;
    const int tid = threadIdx.x;

    // load values; accumulate valid count + total valid sum on the fly
    float mcnt = 0.0f, msum = 0.0f;
    for (int j = tid; j < kNumNeg; j += kTpbSel) {
        unsigned v = gvals[(size_t)b * kNumNeg + j];
        s[j] = v;
        if (v != kSentinel) { mcnt += 1.0f; msum += __uint_as_float(v); }
    }
    // partials reduce (128 slots; tids < 128 contribute)
    float c = 0.0f, p = 0.0f;
    if (tid < kBlocksPerB) {
        const float* slot = partials + ((size_t)b * kBlocksPerB + tid) * 2;
        c = slot[0]; p = slot[1];
    }
    // block-reduce 4 values
    #pragma unroll
    for (int off = 32; off > 0; off >>= 1) {
        mcnt += __shfl_down(mcnt, off);
        msum += __shfl_down(msum, off);
        c    += __shfl_down(c, off);
        p    += __shfl_down(p, off);
    }
    const int wave = tid / 64, lane = tid % 64;
    __shared__ float r0[kTpbSel / 64], r1[kTpbSel / 64], r2[kTpbSel / 64], r3[kTpbSel / 64];
    if (lane == 0) { r0[wave] = mcnt; r1[wave] = msum; r2[wave] = c; r3[wave] = p; }
    __syncthreads();
    if (tid == 0) {
        float a0 = 0, a1 = 0, a2 = 0, a3 = 0;
        for (int w = 0; w < kTpbSel / 64; ++w) { a0 += r0[w]; a1 += r1[w]; a2 += r2[w]; a3 += r3[w]; }
        sh_m = a0; sh_sumall = a1; sh_np = a2; sh_ps = a3;
        const int num_pos = (int)a2;
        const int m = (int)a0;
        const int k = (num_pos > 0) ? min(kRatio * num_pos, kNumNeg) : kNumHard;
        if (k >= m) {
            // keep every valid value
            batch_loss[b] = (a3 + a1) / fmaxf(a2, 1.0f);
            sh_done = 1;
        } else {
            sh_done = 0;
            sh_krem = (unsigned)k;
            sh_prefix = 0u;
            sh_mask = 0u;
        }
    }
    __syncthreads();
    if (sh_done) return;

    // 4-pass MSB radix select: find t = k-th largest among valid values
    #pragma unroll
    for (int pass = 0; pass < 4; ++pass) {
        const int shift = 24 - 8 * pass;
        if (tid < 256) hist[tid] = 0u;
        __syncthreads();
        const unsigned pmask = sh_mask, pval = sh_prefix;
        for (int j = tid; j < kNumNeg; j += kTpbSel) {
            unsigned v = s[j];
            if (v != kSentinel && (v & pmask) == pval)
                atomicAdd(&hist[(v >> shift) & 255u], 1u);
        }
        __syncthreads();
        if (tid == 0) {
            unsigned krem = sh_krem, cum = 0;
            int bsel = 255;
            for (; bsel >= 0; --bsel) {
                unsigned h = hist[bsel];
                if (cum + h >= krem) break;
                cum += h;
            }
            if (bsel < 0) bsel = 0;              // safety (can't happen: k < m)
            sh_krem = krem - cum;                // rank within chosen bucket
            sh_prefix = pval | ((unsigned)bsel << shift);
            sh_mask = pmask | (0xFFu << shift);
        }
        __syncthreads();
    }

    // t = exact k-th largest bit pattern; sum all strictly-greater values
    const unsigned tbits = sh_prefix;
    float gsum = 0.0f;
    for (int j = tid; j < kNumNeg; j += kTpbSel) {
        unsigned v = s[j];
        if (v != kSentinel && v > tbits) gsum += __uint_as_float(v);
    }
    #pragma unroll
    for (int off = 32; off > 0; off >>= 1) gsum += __shfl_down(gsum, off);
    if (lane == 0) red[wave] = gsum;
    __syncthreads();
    if (tid == 0) {
        float sum_gt = 0.0f;
        for (int w = 0; w < kTpbSel / 64; ++w) sum_gt += red[w];
        const float tval = __uint_as_float(tbits);
        const float neg_sum = sum_gt + (float)sh_krem * tval;
        batch_loss[b] = (sh_ps + neg_sum) / fmaxf(sh_np, 1.0f);
    }
}

__global__ void finalize_kernel(const float* __restrict__ batch_loss,
                                float* __restrict__ out) {
    if (threadIdx.x == 0) {
        float s = 0.0f;
        for (int b = 0; b < kB; ++b) s += batch_loss[b];
        out[0] = s / (float)kB;
    }
}

} // namespace

extern "C" void kernel_launch(void* const* d_in, const int* in_sizes, int n_in,
                              void* d_out, int out_size, void* d_ws, size_t ws_size,
                              hipStream_t stream) {
    const float* pred   = (const float*)d_in[0];
    const float* target = (const float*)d_in[1];
    const float* mask   = (const float*)d_in[2];
    const int*   negidx = (const int*)d_in[3];
    float* ws = (float*)d_ws;
    float*    partials   = ws;                            // 8*128*2 floats
    float*    batch_loss = ws + kB * kBlocksPerB * 2;     // 8 floats
    unsigned* gvals      = (unsigned*)(ws + kB * kBlocksPerB * 2 + 16);
    float* out = (float*)d_out;

    dim3 gridA(kBlocksPerB, kB);
    pos_reduce_kernel<<<gridA, dim3(kTpbA), 0, stream>>>(pred, target, mask, partials);
    dim3 gridG((kNumNeg + 255) / 256, kB);
    gather_kernel<<<gridG, dim3(256), 0, stream>>>(pred, target, mask, negidx, gvals);
    select_kernel<<<dim3(kB), dim3(kTpbSel), 0, stream>>>(gvals, partials, batch_loss);
    finalize_kernel<<<1, 64, 0, stream>>>(batch_loss, out);
}

// Round 3
// 33.201 us; speedup vs baseline: 7.6824x; 2.0579x over previous
//
#include <hip/hip_runtime.h>
#include <math.h>

namespace {

constexpr float kAlpha   = 0.75f;
constexpr int   kNumNeg  = 10000;
constexpr int   kNumHard = 100;
constexpr int   kRatio   = 100;
constexpr int   kB       = 8;
constexpr int   kN       = 64 * 128 * 128;   // 1048576
constexpr int   kBlocksPerB = 128;
constexpr int   kTpbA    = 256;
constexpr int   kTpbSel  = 1024;
constexpr int   kWavesSel = kTpbSel / 64;    // 16
constexpr unsigned kSentinel = 0xFFFFFFFFu;  // pos-in-idx marker

__device__ __forceinline__ float loss_at(float pred, float target, float mask) {
    float prob = 1.0f / (1.0f + expf(-pred));
    prob = fminf(fmaxf(prob, 1.0e-4f), 1.0f - 1.0e-4f);
    bool pos = (target == 1.0f);
    float alpha_f = pos ? kAlpha : (1.0f - kAlpha);
    float pt = pos ? (1.0f - prob) : prob;
    float focal_w = alpha_f * pt * pt;
    float bce = fmaxf(pred, 0.0f) - pred * target + log1pf(expf(-fabsf(pred)));
    float loss = (mask == 0.0f) ? focal_w * bce : 0.0f;
    if (pos && prob < 0.8f) loss *= 4.0f;
    return loss;
}

// Stage A: per-(batch, block) partial num_pos / pos_sum. Streams only `target`.
__global__ void __launch_bounds__(kTpbA) pos_reduce_kernel(
        const float* __restrict__ pred, const float* __restrict__ target,
        const float* __restrict__ mask, float* __restrict__ partials) {
    const int b = blockIdx.y;
    const size_t base = (size_t)b * kN;
    const float4* t4 = (const float4*)(target + base);
    const int nvec = kN / 4;

    float cnt = 0.0f, psum = 0.0f;
    for (int i = blockIdx.x * kTpbA + threadIdx.x; i < nvec; i += kTpbA * kBlocksPerB) {
        float4 tv = t4[i];
        float tvv[4] = {tv.x, tv.y, tv.z, tv.w};
        #pragma unroll
        for (int c = 0; c < 4; ++c) {
            if (tvv[c] == 1.0f) {
                int gi = i * 4 + c;
                cnt += 1.0f;
                psum += loss_at(pred[base + gi], 1.0f, mask[base + gi]);
            }
        }
    }
    #pragma unroll
    for (int off = 32; off > 0; off >>= 1) {
        cnt  += __shfl_down(cnt, off);
        psum += __shfl_down(psum, off);
    }
    __shared__ float sc[kTpbA / 64], sp[kTpbA / 64];
    const int wave = threadIdx.x / 64, lane = threadIdx.x % 64;
    if (lane == 0) { sc[wave] = cnt; sp[wave] = psum; }
    __syncthreads();
    if (threadIdx.x == 0) {
        float c = 0.0f, p = 0.0f;
        for (int w = 0; w < kTpbA / 64; ++w) { c += sc[w]; p += sp[w]; }
        float* slot = partials + ((size_t)b * kBlocksPerB + blockIdx.x) * 2;
        slot[0] = c; slot[1] = p;
    }
}

// Stage B: spread the random gathers over many CUs.
__global__ void __launch_bounds__(256) gather_kernel(
        const float* __restrict__ pred, const float* __restrict__ target,
        const float* __restrict__ mask, const int* __restrict__ neg_idx,
        unsigned* __restrict__ gvals) {
    const int b = blockIdx.y;
    const int j = blockIdx.x * blockDim.x + threadIdx.x;
    if (j >= kNumNeg) return;
    const size_t base = (size_t)b * kN;
    const int gi = neg_idx[(size_t)b * kNumNeg + j];
    const float tg = target[base + gi];
    unsigned outv;
    if (tg == 1.0f) {
        outv = kSentinel;
    } else {
        float v = loss_at(pred[base + gi], tg, mask[base + gi]);
        outv = __float_as_uint(v);               // v >= 0, finite
    }
    gvals[(size_t)b * kNumNeg + j] = outv;
}

// Stage C: one block per batch. Exact top-k sum via 4-pass radix select with
// per-wave privatized histograms and a fully-parallel bucket scan.
__global__ void __launch_bounds__(kTpbSel) select_kernel(
        const unsigned* __restrict__ gvals, const float* __restrict__ partials,
        float* __restrict__ batch_loss) {
    __shared__ unsigned s[kNumNeg];                      // 40 KB
    __shared__ unsigned whist[kWavesSel][256];           // 16 KB
    __shared__ unsigned hist_total[256];
    __shared__ unsigned sfx[256];                        // suffix-inclusive sums
    __shared__ float r0[kWavesSel], r1[kWavesSel], r2[kWavesSel], r3[kWavesSel];
    __shared__ float red[kWavesSel];
    __shared__ float sh_np, sh_ps;
    __shared__ unsigned sh_krem, sh_prefix;
    __shared__ int sh_done;

    const int b = blockIdx.x;
    const int tid = threadIdx.x;
    const int wave = tid >> 6, lane = tid & 63;

    // zero per-wave histograms (used by pass 0, filled during load)
    for (int i = tid; i < kWavesSel * 256; i += kTpbSel)
        ((unsigned*)whist)[i] = 0u;
    __syncthreads();

    // load values; valid count + total valid sum + pass-0 histogram on the fly
    float mcnt = 0.0f, msum = 0.0f;
    for (int j = tid; j < kNumNeg; j += kTpbSel) {
        unsigned v = gvals[(size_t)b * kNumNeg + j];
        s[j] = v;
        if (v != kSentinel) {
            mcnt += 1.0f;
            msum += __uint_as_float(v);
            atomicAdd(&whist[wave][v >> 24], 1u);        // v>=0 so (v>>24)<128
        }
    }
    float c = 0.0f, p = 0.0f;
    if (tid < kBlocksPerB) {
        const float* slot = partials + ((size_t)b * kBlocksPerB + tid) * 2;
        c = slot[0]; p = slot[1];
    }
    #pragma unroll
    for (int off = 32; off > 0; off >>= 1) {
        mcnt += __shfl_down(mcnt, off);
        msum += __shfl_down(msum, off);
        c    += __shfl_down(c, off);
        p    += __shfl_down(p, off);
    }
    if (lane == 0) { r0[wave] = mcnt; r1[wave] = msum; r2[wave] = c; r3[wave] = p; }
    __syncthreads();   // covers r*, s[], whist atomics
    if (tid == 0) {
        float a0 = 0, a1 = 0, a2 = 0, a3 = 0;
        for (int w = 0; w < kWavesSel; ++w) { a0 += r0[w]; a1 += r1[w]; a2 += r2[w]; a3 += r3[w]; }
        sh_np = a2; sh_ps = a3;
        const int num_pos = (int)a2;
        const int m = (int)a0;
        const int k = (num_pos > 0) ? min(kRatio * num_pos, kNumNeg) : kNumHard;
        if (k >= m) {
            batch_loss[b] = (a3 + a1) / fmaxf(a2, 1.0f);
            sh_done = 1;
        } else {
            sh_done = 0;
            sh_krem = (unsigned)k;
            sh_prefix = 0u;
        }
    }
    __syncthreads();
    if (sh_done) return;

    // 4-pass MSB radix select; pass 0 histogram already built.
    #pragma unroll
    for (int pass = 0; pass < 4; ++pass) {
        const int shift = 24 - 8 * pass;
        if (pass > 0) {
            for (int i = tid; i < kWavesSel * 256; i += kTpbSel)
                ((unsigned*)whist)[i] = 0u;
            __syncthreads();
            const unsigned pmask = 0xFFFFFFFFu << (shift + 8);
            const unsigned pval = sh_prefix;
            for (int j = tid; j < kNumNeg; j += kTpbSel) {
                unsigned v = s[j];
                if (v != kSentinel && (v & pmask) == pval)
                    atomicAdd(&whist[wave][(v >> shift) & 255u], 1u);
            }
        }
        __syncthreads();
        // reduce per-wave hists
        if (tid < 256) {
            unsigned h = 0;
            #pragma unroll
            for (int w = 0; w < kWavesSel; ++w) h += whist[w][tid];
            hist_total[tid] = h;
        }
        __syncthreads();
        // wave 0: suffix-inclusive sums sfx[t] = sum_{j>=t} hist_total[j]
        if (wave == 0) {
            unsigned v0 = hist_total[255 - (4 * lane + 0)];
            unsigned v1 = hist_total[255 - (4 * lane + 1)];
            unsigned v2 = hist_total[255 - (4 * lane + 2)];
            unsigned v3 = hist_total[255 - (4 * lane + 3)];
            unsigned p0 = v0, p1 = p0 + v1, p2 = p1 + v2, p3 = p2 + v3;
            unsigned acc = p3;
            #pragma unroll
            for (int off = 1; off < 64; off <<= 1) {
                unsigned y = __shfl_up(acc, off);
                if (lane >= off) acc += y;
            }
            unsigned excl = acc - p3;
            sfx[255 - (4 * lane + 0)] = excl + p0;
            sfx[255 - (4 * lane + 1)] = excl + p1;
            sfx[255 - (4 * lane + 2)] = excl + p2;
            sfx[255 - (4 * lane + 3)] = excl + p3;
        }
        __syncthreads();
        const unsigned krem = sh_krem;   // snapshot BEFORE anyone rewrites it
        __syncthreads();
        if (tid < 256) {
            unsigned si = sfx[tid];
            bool sel = (si >= krem) && (tid == 255 || sfx[tid + 1] < krem);
            if (sel) {
                sh_krem = krem - (si - hist_total[tid]);   // rank within bucket
                sh_prefix |= (unsigned)tid << shift;
            }
        }
        __syncthreads();
    }

    // t = exact k-th largest bit pattern; sum all strictly-greater values
    const unsigned tbits = sh_prefix;
    float gsum = 0.0f;
    for (int j = tid; j < kNumNeg; j += kTpbSel) {
        unsigned v = s[j];
        if (v != kSentinel && v > tbits) gsum += __uint_as_float(v);
    }
    #pragma unroll
    for (int off = 32; off > 0; off >>= 1) gsum += __shfl_down(gsum, off);
    if (lane == 0) red[wave] = gsum;
    __syncthreads();
    if (tid == 0) {
        float sum_gt = 0.0f;
        for (int w = 0; w < kWavesSel; ++w) sum_gt += red[w];
        const float tval = __uint_as_float(tbits);
        const float neg_sum = sum_gt + (float)sh_krem * tval;
        batch_loss[b] = (sh_ps + neg_sum) / fmaxf(sh_np, 1.0f);
    }
}

__global__ void finalize_kernel(const float* __restrict__ batch_loss,
                                float* __restrict__ out) {
    if (threadIdx.x == 0) {
        float s = 0.0f;
        for (int b = 0; b < kB; ++b) s += batch_loss[b];
        out[0] = s / (float)kB;
    }
}

} // namespace

extern "C" void kernel_launch(void* const* d_in, const int* in_sizes, int n_in,
                              void* d_out, int out_size, void* d_ws, size_t ws_size,
                              hipStream_t stream) {
    const float* pred   = (const float*)d_in[0];
    const float* target = (const float*)d_in[1];
    const float* mask   = (const float*)d_in[2];
    const int*   negidx = (const int*)d_in[3];
    float* ws = (float*)d_ws;
    float*    partials   = ws;                            // 8*128*2 floats
    float*    batch_loss = ws + kB * kBlocksPerB * 2;     // 8 floats
    unsigned* gvals      = (unsigned*)(ws + kB * kBlocksPerB * 2 + 16);
    float* out = (float*)d_out;

    dim3 gridA(kBlocksPerB, kB);
    pos_reduce_kernel<<<gridA, dim3(kTpbA), 0, stream>>>(pred, target, mask, partials);
    dim3 gridG((kNumNeg + 255) / 256, kB);
    gather_kernel<<<gridG, dim3(256), 0, stream>>>(pred, target, mask, negidx, gvals);
    select_kernel<<<dim3(kB), dim3(kTpbSel), 0, stream>>>(gvals, partials, batch_loss);
    finalize_kernel<<<1, 64, 0, stream>>>(batch_loss, out);
}

// Round 4
// 30.284 us; speedup vs baseline: 8.4223x; 1.0963x over previous
//
#include <hip/hip_runtime.h>
#include <math.h>

namespace {

constexpr float kAlpha   = 0.75f;
constexpr int   kNumNeg  = 10000;
constexpr int   kNumHard = 100;
constexpr int   kRatio   = 100;
constexpr int   kB       = 8;
constexpr int   kN       = 64 * 128 * 128;   // 1048576
constexpr int   kBlocksPerB = 128;
constexpr int   kPosBlocks  = kB * kBlocksPerB;        // 1024
constexpr int   kGatherBlocks = (kB * kNumNeg + 255) / 256;  // 313
constexpr int   kTpb1    = 256;
constexpr int   kTpbSel  = 1024;
constexpr int   kWavesSel = kTpbSel / 64;    // 16
constexpr int   kVPerThread = (kNumNeg + kTpbSel - 1) / kTpbSel;  // 10
constexpr unsigned kSentinel = 0xFFFFFFFFu;  // pos-in-idx marker

__device__ __forceinline__ float loss_at(float pred, float target, float mask) {
    float prob = 1.0f / (1.0f + expf(-pred));
    prob = fminf(fmaxf(prob, 1.0e-4f), 1.0f - 1.0e-4f);
    bool pos = (target == 1.0f);
    float alpha_f = pos ? kAlpha : (1.0f - kAlpha);
    float pt = pos ? (1.0f - prob) : prob;
    float focal_w = alpha_f * pt * pt;
    float bce = fmaxf(pred, 0.0f) - pred * target + log1pf(expf(-fabsf(pred)));
    float loss = (mask == 0.0f) ? focal_w * bce : 0.0f;
    if (pos && prob < 0.8f) loss *= 4.0f;
    return loss;
}

// Stage 1 (fused): blocks [0,1024) stream `target` for num_pos/pos_sum
// partials; blocks [1024,1337) do the random gather of candidate losses.
// Also resets the arrival counter used by stage 2.
__global__ void __launch_bounds__(kTpb1) stage1_kernel(
        const float* __restrict__ pred, const float* __restrict__ target,
        const float* __restrict__ mask, const int* __restrict__ neg_idx,
        float* __restrict__ partials, unsigned* __restrict__ gvals,
        unsigned* __restrict__ counter) {
    const int blk = blockIdx.x;
    if (blk == 0 && threadIdx.x == 0) *counter = 0u;   // visible at kernel end

    if (blk < kPosBlocks) {
        const int b = blk >> 7;
        const int slice = blk & 127;
        const size_t base = (size_t)b * kN;
        const float4* t4 = (const float4*)(target + base);
        const int nvec = kN / 4;

        float cnt = 0.0f, psum = 0.0f;
        for (int i = slice * kTpb1 + threadIdx.x; i < nvec; i += kTpb1 * kBlocksPerB) {
            float4 tv = t4[i];
            float tvv[4] = {tv.x, tv.y, tv.z, tv.w};
            #pragma unroll
            for (int c = 0; c < 4; ++c) {
                if (tvv[c] == 1.0f) {
                    int gi = i * 4 + c;
                    cnt += 1.0f;
                    psum += loss_at(pred[base + gi], 1.0f, mask[base + gi]);
                }
            }
        }
        #pragma unroll
        for (int off = 32; off > 0; off >>= 1) {
            cnt  += __shfl_down(cnt, off);
            psum += __shfl_down(psum, off);
        }
        __shared__ float sc[kTpb1 / 64], sp[kTpb1 / 64];
        const int wave = threadIdx.x / 64, lane = threadIdx.x % 64;
        if (lane == 0) { sc[wave] = cnt; sp[wave] = psum; }
        __syncthreads();
        if (threadIdx.x == 0) {
            float c = 0.0f, p = 0.0f;
            for (int w = 0; w < kTpb1 / 64; ++w) { c += sc[w]; p += sp[w]; }
            float* slot = partials + ((size_t)b * kBlocksPerB + slice) * 2;
            slot[0] = c; slot[1] = p;
        }
    } else {
        const int t = (blk - kPosBlocks) * kTpb1 + threadIdx.x;
        if (t < kB * kNumNeg) {
            const int b = t / kNumNeg;
            const int j = t - b * kNumNeg;
            const size_t base = (size_t)b * kN;
            const int gi = neg_idx[(size_t)b * kNumNeg + j];
            const float tg = target[base + gi];
            unsigned outv;
            if (tg == 1.0f) {
                outv = kSentinel;
            } else {
                float v = loss_at(pred[base + gi], tg, mask[base + gi]);
                outv = __float_as_uint(v);       // v >= 0, finite
            }
            gvals[(size_t)b * kNumNeg + j] = outv;
        }
    }
}

// Stage 2: one block per batch. Exact top-k sum via 4-pass radix select.
// Candidate values live in registers; LDS holds only histograms.
// Last-arriving block computes the final mean (fused finalize).
__global__ void __launch_bounds__(kTpbSel) select_kernel(
        const unsigned* __restrict__ gvals, const float* __restrict__ partials,
        float* __restrict__ batch_loss, unsigned* __restrict__ counter,
        float* __restrict__ out) {
    __shared__ unsigned whist[kWavesSel][256];           // 16 KB
    __shared__ unsigned hist_total[256];
    __shared__ unsigned sfx[256];
    __shared__ float r0[kWavesSel], r1[kWavesSel], r2[kWavesSel], r3[kWavesSel];
    __shared__ float red[kWavesSel];
    __shared__ float sh_np, sh_ps;
    __shared__ unsigned sh_krem, sh_prefix;
    __shared__ int sh_done;

    const int b = blockIdx.x;
    const int tid = threadIdx.x;
    const int wave = tid >> 6, lane = tid & 63;

    for (int i = tid; i < kWavesSel * 256; i += kTpbSel)
        ((unsigned*)whist)[i] = 0u;
    __syncthreads();

    // load candidates into registers; count/sum valid; pass-0 histogram
    unsigned vreg[kVPerThread];
    float mcnt = 0.0f, msum = 0.0f;
    #pragma unroll
    for (int it = 0; it < kVPerThread; ++it) {
        const int j = tid + it * kTpbSel;
        unsigned v = kSentinel;
        if (j < kNumNeg) v = gvals[(size_t)b * kNumNeg + j];
        vreg[it] = v;
        if (v != kSentinel) {
            mcnt += 1.0f;
            msum += __uint_as_float(v);
            atomicAdd(&whist[wave][v >> 24], 1u);        // v>=0 → bucket <128
        }
    }
    float c = 0.0f, p = 0.0f;
    if (tid < kBlocksPerB) {
        const float* slot = partials + ((size_t)b * kBlocksPerB + tid) * 2;
        c = slot[0]; p = slot[1];
    }
    #pragma unroll
    for (int off = 32; off > 0; off >>= 1) {
        mcnt += __shfl_down(mcnt, off);
        msum += __shfl_down(msum, off);
        c    += __shfl_down(c, off);
        p    += __shfl_down(p, off);
    }
    if (lane == 0) { r0[wave] = mcnt; r1[wave] = msum; r2[wave] = c; r3[wave] = p; }
    __syncthreads();
    float my_loss = 0.0f;          // only thread 0's value is used
    if (tid == 0) {
        float a0 = 0, a1 = 0, a2 = 0, a3 = 0;
        for (int w = 0; w < kWavesSel; ++w) { a0 += r0[w]; a1 += r1[w]; a2 += r2[w]; a3 += r3[w]; }
        sh_np = a2; sh_ps = a3;
        const int num_pos = (int)a2;
        const int m = (int)a0;
        const int k = (num_pos > 0) ? min(kRatio * num_pos, kNumNeg) : kNumHard;
        if (k >= m) {
            my_loss = (a3 + a1) / fmaxf(a2, 1.0f);
            sh_done = 1;
        } else {
            sh_done = 0;
            sh_krem = (unsigned)k;
            sh_prefix = 0u;
        }
    }
    __syncthreads();

    if (!sh_done) {
        // 4-pass MSB radix select (pass-0 histogram already built)
        #pragma unroll
        for (int pass = 0; pass < 4; ++pass) {
            const int shift = 24 - 8 * pass;
            if (pass > 0) {
                for (int i = tid; i < kWavesSel * 256; i += kTpbSel)
                    ((unsigned*)whist)[i] = 0u;
                __syncthreads();
                const unsigned pmask = 0xFFFFFFFFu << (shift + 8);
                const unsigned pval = sh_prefix;
                #pragma unroll
                for (int it = 0; it < kVPerThread; ++it) {
                    unsigned v = vreg[it];
                    if (v != kSentinel && (v & pmask) == pval)
                        atomicAdd(&whist[wave][(v >> shift) & 255u], 1u);
                }
            }
            __syncthreads();
            if (tid < 256) {
                unsigned h = 0;
                #pragma unroll
                for (int w = 0; w < kWavesSel; ++w) h += whist[w][tid];
                hist_total[tid] = h;
            }
            __syncthreads();
            // wave 0: suffix-inclusive sums sfx[t] = sum_{j>=t} hist_total[j]
            if (wave == 0) {
                unsigned v0 = hist_total[255 - (4 * lane + 0)];
                unsigned v1 = hist_total[255 - (4 * lane + 1)];
                unsigned v2 = hist_total[255 - (4 * lane + 2)];
                unsigned v3 = hist_total[255 - (4 * lane + 3)];
                unsigned p0 = v0, p1 = p0 + v1, p2 = p1 + v2, p3 = p2 + v3;
                unsigned acc = p3;
                #pragma unroll
                for (int off = 1; off < 64; off <<= 1) {
                    unsigned y = __shfl_up(acc, off);
                    if (lane >= off) acc += y;
                }
                unsigned excl = acc - p3;
                sfx[255 - (4 * lane + 0)] = excl + p0;
                sfx[255 - (4 * lane + 1)] = excl + p1;
                sfx[255 - (4 * lane + 2)] = excl + p2;
                sfx[255 - (4 * lane + 3)] = excl + p3;
            }
            __syncthreads();
            const unsigned krem = sh_krem;   // snapshot before rewrite
            __syncthreads();
            if (tid < 256) {
                unsigned si = sfx[tid];
                bool sel = (si >= krem) && (tid == 255 || sfx[tid + 1] < krem);
                if (sel) {
                    sh_krem = krem - (si - hist_total[tid]);
                    sh_prefix |= (unsigned)tid << shift;
                }
            }
            __syncthreads();
        }

        // t = exact k-th largest bit pattern; sum strictly-greater values
        const unsigned tbits = sh_prefix;
        float gsum = 0.0f;
        #pragma unroll
        for (int it = 0; it < kVPerThread; ++it) {
            unsigned v = vreg[it];
            if (v != kSentinel && v > tbits) gsum += __uint_as_float(v);
        }
        #pragma unroll
        for (int off = 32; off > 0; off >>= 1) gsum += __shfl_down(gsum, off);
        if (lane == 0) red[wave] = gsum;
        __syncthreads();
        if (tid == 0) {
            float sum_gt = 0.0f;
            for (int w = 0; w < kWavesSel; ++w) sum_gt += red[w];
            const float tval = __uint_as_float(sh_prefix);
            const float neg_sum = sum_gt + (float)sh_krem * tval;
            my_loss = (sh_ps + neg_sum) / fmaxf(sh_np, 1.0f);
        }
    }

    // fused finalize: last-arriving block computes the mean
    if (tid == 0) {
        __hip_atomic_store(&batch_loss[b], my_loss, __ATOMIC_RELEASE,
                           __HIP_MEMORY_SCOPE_AGENT);
        unsigned old = __hip_atomic_fetch_add(counter, 1u, __ATOMIC_ACQ_REL,
                                              __HIP_MEMORY_SCOPE_AGENT);
        if (old == (unsigned)(kB - 1)) {
            float s = 0.0f;
            for (int i = 0; i < kB; ++i)
                s += __hip_atomic_load(&batch_loss[i], __ATOMIC_ACQUIRE,
                                       __HIP_MEMORY_SCOPE_AGENT);
            out[0] = s / (float)kB;
        }
    }
}

} // namespace

extern "C" void kernel_launch(void* const* d_in, const int* in_sizes, int n_in,
                              void* d_out, int out_size, void* d_ws, size_t ws_size,
                              hipStream_t stream) {
    const float* pred   = (const float*)d_in[0];
    const float* target = (const float*)d_in[1];
    const float* mask   = (const float*)d_in[2];
    const int*   negidx = (const int*)d_in[3];
    float* ws = (float*)d_ws;
    float*    partials   = ws;                         // 2048 floats
    float*    batch_loss = ws + 2048;                  // 8 floats
    unsigned* counter    = (unsigned*)(ws + 2056);     // 1 uint
    unsigned* gvals      = (unsigned*)(ws + 2064);     // 80000 uints
    float* out = (float*)d_out;

    stage1_kernel<<<dim3(kPosBlocks + kGatherBlocks), dim3(kTpb1), 0, stream>>>(
        pred, target, mask, negidx, partials, gvals, counter);
    select_kernel<<<dim3(kB), dim3(kTpbSel), 0, stream>>>(
        gvals, partials, batch_loss, counter, out);
}